// Round 10
// baseline (2080.616 us; speedup 1.0000x reference)
//
#include <hip/hip_runtime.h>

typedef __attribute__((ext_vector_type(8))) short shortx8;
typedef __attribute__((ext_vector_type(4))) float floatx4;
typedef __attribute__((ext_vector_type(4))) unsigned uintx4;

constexpr int NAc = 4096;     // atoms
constexpr int NEc = 65536;    // edges
constexpr int NTc = 262144;   // triplets
constexpr float PI_F = 3.14159265358979323846f;
constexpr float SQ25 = 0.63245553203367587f;   // sqrt(2/5)

__device__ __forceinline__ float bf2f(unsigned short h){ return __uint_as_float(((unsigned)h)<<16); }
__device__ __forceinline__ unsigned short f2bf(float f){
  unsigned u = __float_as_uint(f);
  u += 0x7fffu + ((u>>16)&1u);
  return (unsigned short)(u>>16);
}
__device__ __forceinline__ float swishf(float x){ return x/(1.f+__expf(-x)); }

__device__ __forceinline__ floatx4 mfma16x16x32bf(shortx8 a, shortx8 b, floatx4 c){
  floatx4 d;
  asm("v_mfma_f32_16x16x32_bf16 %0, %1, %2, %3" : "=v"(d) : "v"(a), "v"(b), "v"(c));
  return d;
}

// ---------------- geometry ----------------
__global__ __launch_bounds__(256)
void egeom_k(const float* __restrict__ R, const int* __restrict__ ei,
             const int* __restrict__ ej, float* __restrict__ Dij, float* __restrict__ rbf){
  int e = blockIdx.x*256 + threadIdx.x;
  int i = ei[e], j = ej[e];
  float dx = R[i*3+0]-R[j*3+0];
  float dy = R[i*3+1]-R[j*3+1];
  float dz = R[i*3+2]-R[j*3+2];
  float d2 = dx*dx+dy*dy+dz*dz;
  float D = sqrtf(fmaxf(d2, 0.f));
  Dij[e] = D;
  float d = fmaxf(D, 1e-6f);
  float s = PI_F*d*0.2f;
  float sn, cs; sincosf(s, &sn, &cs);
  float invd = SQ25/d;
  float sprev = 0.f, scur = sn;
  #pragma unroll
  for (int q=0;q<6;q++){
    rbf[e*6+q] = scur*invd;
    float nx = 2.f*cs*scur - sprev; sprev = scur; scur = nx;
  }
}

// sorted-order triplet geometry: thread p handles w = tperm[p].
// Writes angp[p][16] AoS (coalesced) + tmeta[p] = texp[w].
__global__ __launch_bounds__(256)
void tgeom_k(const float* __restrict__ R, const int* __restrict__ t3i,
             const int* __restrict__ t3j, const int* __restrict__ t3k,
             const int* __restrict__ texp, const int* __restrict__ tperm,
             const float* __restrict__ Dij, float* __restrict__ angp,
             int* __restrict__ tmeta){
  int p = blockIdx.x*256 + threadIdx.x;
  int w = tperm[p];
  int ia = t3i[w], ja = t3j[w], ka = t3k[w];
  int e  = texp[w];
  tmeta[p] = e;
  float xi = R[ia*3+0], yi = R[ia*3+1], zi = R[ia*3+2];
  float r1x = R[ja*3+0]-xi, r1y = R[ja*3+1]-yi, r1z = R[ja*3+2]-zi;
  float r2x = R[ka*3+0]-xi, r2y = R[ka*3+1]-yi, r2z = R[ka*3+2]-zi;
  float dt = r1x*r2x + r1y*r2y + r1z*r2z;
  float cx = r1y*r2z - r1z*r2y;
  float cy = r1z*r2x - r1x*r2z;
  float cz = r1x*r2y - r1y*r2x;
  float yv = sqrtf(cx*cx + cy*cy + cz*cz);
  float h = sqrtf(dt*dt + yv*yv);
  float c1 = (h > 0.f) ? dt/h : 1.f;   // cos(atan2(y,x))
  float f[16];
  f[0] = 1.f; f[1] = c1;
  float cprev = 1.f, ccur = c1;
  #pragma unroll
  for (int l=2;l<7;l++){
    float nx = 2.f*c1*ccur - cprev; cprev = ccur; ccur = nx;
    f[l] = nx;
  }
  float d = fmaxf(Dij[e], 1e-6f);
  float s = PI_F*d*0.2f;
  float sn, cs; sincosf(s, &sn, &cs);
  float invd = 1.f/d;
  float sprev = 0.f, scur = sn;
  #pragma unroll
  for (int q=0;q<7;q++){
    f[7+q] = scur*invd;
    float nx = 2.f*cs*scur - sprev; sprev = scur; scur = nx;
  }
  f[14] = 0.f; f[15] = 0.f;
  float4* op = (float4*)(angp + (size_t)p*16);
  op[0] = (float4){f[0],f[1],f[2],f[3]};
  op[1] = (float4){f[4],f[5],f[6],f[7]};
  op[2] = (float4){f[8],f[9],f[10],f[11]};
  op[3] = (float4){f[12],f[13],f[14],f[15]};
}

// ---------------- weight prep (fp32 -> bf16, transpose to [N,K]) ----------------
// Wjk: concat [ji rows 0..127 | kj rows 128..255] per layer
__global__ __launch_bounds__(256)
void prep_transpose(const float* __restrict__ Wemb, const float* __restrict__ Wji,
                    const float* __restrict__ Wkj, const float* __restrict__ Wfin,
                    unsigned short* __restrict__ dW12, unsigned short* __restrict__ dWjk,
                    unsigned short* __restrict__ dWfin){
  int y = blockIdx.y;
  int x = blockIdx.x*256 + threadIdx.x;
  if (y == 0){
    if (x < 32768){
      int n = x >> 8, k = x & 255;
      dW12[x] = f2bf(Wemb[k*128 + n]);
    }
  } else {
    if (x < 16384){
      int n = x >> 7, k = x & 127;
      const float* s; unsigned short* d;
      if (y <= 7)      { s = Wji  + (y-1)*16384;  d = dWjk  + (y-1)*32768; }
      else if (y <= 14){ s = Wkj  + (y-8)*16384;  d = dWjk  + (y-8)*32768 + 16384; }
      else             { s = Wfin + (y-15)*16384; d = dWfin + (y-15)*16384; }
      d[x] = f2bf(s[k*128 + n]);
    }
  }
}

// Wbil [j,l,i] -> Wbilt [i][k=(j*8+l)]  (plain [1024,128] transpose per layer)
__global__ __launch_bounds__(256)
void prep_wbil(const float* __restrict__ Wbil, unsigned short* __restrict__ dst){
  int x = blockIdx.x*256 + threadIdx.x;
  if (x < 7*131072){
    int i = x >> 17; int rem = x & 131071;
    int o = rem >> 10; int k = rem & 1023;
    dst[x] = f2bf(Wbil[(size_t)i*131072 + (size_t)k*128 + o]);
  }
}

__global__ __launch_bounds__(256)
void prep_emb(const float* __restrict__ emb, unsigned short* __restrict__ d){
  int x = blockIdx.x*256 + threadIdx.x;
  if (x < 95*128) d[x] = f2bf(emb[x]);
}

// ---------------- counting sort ----------------
__global__ __launch_bounds__(256)
void hist_k(const int* __restrict__ ids, int n, int* __restrict__ hist){
  int stride = gridDim.x*blockDim.x;
  for (int x = blockIdx.x*blockDim.x + threadIdx.x; x < n; x += stride)
    atomicAdd(&hist[ids[x]], 1);
}

// hierarchical scan: nbins <= 65536, nbins % 256 == 0, nbins/256 <= 256
__global__ __launch_bounds__(256)
void scan1_k(const int* __restrict__ hist, int* __restrict__ offs, int* __restrict__ bsum){
  __shared__ int buf[256];
  int t = threadIdx.x;
  int x = blockIdx.x*256 + t;
  int v = hist[x];
  buf[t] = v; __syncthreads();
  #pragma unroll
  for (int d=1; d<256; d<<=1){
    int u = (t>=d) ? buf[t-d] : 0;
    __syncthreads(); buf[t] += u; __syncthreads();
  }
  offs[x] = buf[t] - v;                 // exclusive within block
  if (t == 255) bsum[blockIdx.x] = buf[255];
}

__global__ __launch_bounds__(256)
void scan2_k(int* __restrict__ bsum, int nb){
  __shared__ int buf[256];
  int t = threadIdx.x;
  int v = (t < nb) ? bsum[t] : 0;
  buf[t] = v; __syncthreads();
  #pragma unroll
  for (int d=1; d<256; d<<=1){
    int u = (t>=d) ? buf[t-d] : 0;
    __syncthreads(); buf[t] += u; __syncthreads();
  }
  if (t < nb) bsum[t] = buf[t] - v;     // exclusive
}

__global__ __launch_bounds__(256)
void scan3_k(const int* __restrict__ hist, int* __restrict__ offs,
             const int* __restrict__ bsum, int nbins){
  int x = blockIdx.x*256 + threadIdx.x;
  int o = offs[x] + bsum[blockIdx.x];
  offs[x] = o;
  if (x == nbins-1) offs[nbins] = o + hist[x];
}

__global__ __launch_bounds__(256)
void scatter_k(const int* __restrict__ ids, int n, const int* __restrict__ offs,
               int* __restrict__ cursor, int* __restrict__ perm){
  int stride = gridDim.x*blockDim.x;
  for (int x = blockIdx.x*blockDim.x + threadIdx.x; x < n; x += stride){
    int b = ids[x];
    int pos = offs[b] + atomicAdd(&cursor[b], 1);
    perm[pos] = x;
  }
}

// ---------------- sb = sbf @ Wsbf[i]  [T,8] (sorted order, streaming) ----------------
__global__ __launch_bounds__(256)
void sb_k(const float* __restrict__ angp, const float* __restrict__ Wsbf,
          float* __restrict__ sb){
  __shared__ float Ws[392];
  for (int x = threadIdx.x; x < 392; x += 256) Ws[x] = Wsbf[x];
  __syncthreads();
  int p = blockIdx.x*256 + threadIdx.x;
  const float4* ap = (const float4*)(angp + (size_t)p*16);
  float4 a0 = ap[0], a1 = ap[1], a2 = ap[2], a3 = ap[3];
  float ca[7] = {a0.x,a0.y,a0.z,a0.w,a1.x,a1.y,a1.z};
  float rd[7] = {a1.w,a2.x,a2.y,a2.z,a2.w,a3.x,a3.y};
  float o[8] = {0,0,0,0,0,0,0,0};
  #pragma unroll
  for (int a=0;a<7;a++){
    #pragma unroll
    for (int r=0;r<7;r++){
      float pr = ca[a]*rd[r];
      const float* wp = &Ws[(a*7+r)*8];
      #pragma unroll
      for (int l=0;l<8;l++) o[l] += pr*wp[l];
    }
  }
  float4* op = (float4*)(sb + (size_t)p*8);
  op[0] = (float4){o[0],o[1],o[2],o[3]};
  op[1] = (float4){o[4],o[5],o[6],o[7]};
}

// ---------------- fused bilinear v2: 16 edges/block, 32KB LDS -> 5 blocks/CU ----------------
// R9 post-mortem: 64KB LDS capped occupancy at 2 blocks/CU (19.7%); latency-bound gather
// phase had nothing to hide under (MfmaUtil 5%, VALUBusy 14%, HBM 6.5%). v2: M=16,
// LDS 32KB -> 5 blocks/CU (20 waves/CU). Phase 2: one 16-row tile, each wave owns 32 cols.
__global__ __launch_bounds__(256)
void bilin_k(const int* __restrict__ toffs, const int* __restrict__ tmeta,
             const float* __restrict__ sb, const unsigned short* __restrict__ xkj,
             const unsigned short* __restrict__ Wb, const unsigned short* __restrict__ xji,
             unsigned short* __restrict__ afin){
  __shared__ __align__(16) unsigned short Alds[16*1024];   // 32 KB
  const int tid  = threadIdx.x;
  const int lane = tid & 63;
  const int wv   = __builtin_amdgcn_readfirstlane(tid >> 6);
  const int r0   = blockIdx.x*16;

  // ---- phase 1: build 4 rows per wave ----
  for (int ei=0; ei<4; ei++){
    int rl = wv*4 + ei;           // local row (wave-uniform)
    int r  = r0 + rl;
    float a0[8] = {0,0,0,0,0,0,0,0};
    float a1[8] = {0,0,0,0,0,0,0,0};
    int s = toffs[r], e_ = toffs[r+1];
    for (int t = s; t < e_; t++){
      int eidx = tmeta[t];        // uniform -> scalar load
      unsigned xv = *(const unsigned*)&xkj[(size_t)eidx*128 + lane*2];
      float4 s0 = *(const float4*)&sb[(size_t)t*8];
      float4 s1 = *(const float4*)&sb[(size_t)t*8 + 4];
      float x0 = bf2f((unsigned short)(xv & 0xffffu));
      float x1 = bf2f((unsigned short)(xv >> 16));
      a0[0] += s0.x*x0; a1[0] += s0.x*x1;
      a0[1] += s0.y*x0; a1[1] += s0.y*x1;
      a0[2] += s0.z*x0; a1[2] += s0.z*x1;
      a0[3] += s0.w*x0; a1[3] += s0.w*x1;
      a0[4] += s1.x*x0; a1[4] += s1.x*x1;
      a0[5] += s1.y*x0; a1[5] += s1.y*x1;
      a0[6] += s1.z*x0; a1[6] += s1.z*x1;
      a0[7] += s1.w*x0; a1[7] += s1.w*x1;
    }
    // row element k = j*8+l; lane owns j0=2*lane -> elements [16*lane, 16*lane+16)
    unsigned swz = ((unsigned)(rl & 7)) << 4;
    unsigned base = (unsigned)rl*2048u;
    unsigned b0 = base + (((unsigned)lane*32u)       ^ swz);
    unsigned b1 = base + (((unsigned)lane*32u + 16u) ^ swz);
    uintx4 v0, v1;
    #pragma unroll
    for (int d2=0; d2<4; d2++){
      v0[d2] = (unsigned)f2bf(a0[2*d2]) | ((unsigned)f2bf(a0[2*d2+1]) << 16);
      v1[d2] = (unsigned)f2bf(a1[2*d2]) | ((unsigned)f2bf(a1[2*d2+1]) << 16);
    }
    *(uintx4*)((char*)Alds + b0) = v0;
    *(uintx4*)((char*)Alds + b1) = v1;
  }
  __syncthreads();

  // ---- phase 2: GEMM [16,1024] x [128,1024]^T, wave owns cols [wv*32, wv*32+32) ----
  floatx4 acc[2];
  acc[0] = (floatx4){0.f,0.f,0.f,0.f};
  acc[1] = (floatx4){0.f,0.f,0.f,0.f};
  const int g16 = (lane >> 4) << 4;              // byte offset of k-group within 64B
  const int arow = lane & 15;
  const size_t cb0 = (size_t)(wv*32 + (lane & 15))*2048;
  const size_t cb1 = cb0 + 16*2048;
  #pragma unroll 4
  for (int ks=0; ks<32; ks++){
    int kbyte = ks*64 + g16;
    shortx8 af = *(const shortx8*)((const char*)Alds + arow*2048 + (kbyte ^ ((arow & 7) << 4)));
    shortx8 b0 = *(const shortx8*)((const char*)Wb + cb0 + kbyte);
    shortx8 b1 = *(const shortx8*)((const char*)Wb + cb1 + kbyte);
    acc[0] = mfma16x16x32bf(af, b0, acc[0]);
    acc[1] = mfma16x16x32bf(af, b1, acc[1]);
  }
  asm volatile("s_nop 7\ns_nop 7\ns_nop 7");

  // ---- epilogue: afin = acc + xji ----
  #pragma unroll
  for (int j=0;j<4;j++){
    int row = ((lane>>4)<<2) + j;                // C/D: row=(lane>>4)*4+reg
    int grow = r0 + row;
    #pragma unroll
    for (int ni=0;ni<2;ni++){
      int col = wv*32 + ni*16 + (lane & 15);     // C/D: col=lane&15
      size_t oidx = (size_t)grow*128 + col;
      float v = acc[ni][j] + bf2f(xji[oidx]);
      afin[oidx] = f2bf(v);
    }
  }
}

// ---------------- generic MFMA GEMM: C[M,128] = A[M,K] @ Bt[128,K]^T ----------------
// MODE 0: A direct bf16 [rows, K]. MODE 1: embedding gather.
// EPI 0: m0 = swish(acc + b + rbf@Wemb_tail) -> outF(m f32) + outB(m bf16)
// EPI 4: m += swish(acc + bias) -> outF(m) + outB(m bf16)
// EPI 5: dual (grid.y): y0 -> swish(acc+bias) -> outB (xji); y1 -> swish(acc+bias2)*(rbf@W6) -> outB2 (xkj)
template<int MODE, int EPI>
__global__ __launch_bounds__(256)
void gemm_k(const unsigned short* __restrict__ A, const unsigned short* __restrict__ Bt,
            int K, int rowoff, int arow0,
            const int* __restrict__ gi, const int* __restrict__ gj, const int* __restrict__ Zr,
            const float* __restrict__ rbfp, const float* __restrict__ W6,
            const float* __restrict__ bias, const float* __restrict__ bias2,
            const float* minp, const unsigned short* __restrict__ xjip,
            float* outF, unsigned short* outB, unsigned short* outB2){
  __shared__ __align__(16) unsigned short As[128*72];
  __shared__ __align__(16) unsigned short Bs[128*72];
  const int tid = threadIdx.x;
  const int lane = tid & 63;
  const int wid = tid >> 6;
  const int wr = wid >> 1, wc = wid & 1;
  const int rowbase = rowoff + blockIdx.x*128;
  const int brow0 = (EPI==5) ? (int)blockIdx.y*128 : 0;
  floatx4 acc[4][4];
  #pragma unroll
  for (int i=0;i<4;i++)
    #pragma unroll
    for (int j=0;j<4;j++) acc[i][j] = (floatx4){0.f,0.f,0.f,0.f};

  for (int k0 = 0; k0 < K; k0 += 64){
    shortx8 ra[4], rb[4];
    #pragma unroll
    for (int q=0;q<4;q++){
      int c = q*256 + tid;
      int row = c >> 3;
      int ko = (c & 7) << 3;
      const unsigned short* asrc;
      if (MODE == 0){
        asrc = A + (size_t)(rowbase - arow0 + row)*K + k0 + ko;
      } else {
        int grow = rowbase + row;
        int kg = k0 + ko;
        int atom = (kg < 128) ? gi[grow] : gj[grow];
        asrc = A + (size_t)Zr[atom]*128 + (kg & 127);
      }
      ra[q] = *(const shortx8*)asrc;
      rb[q] = *(const shortx8*)(Bt + (size_t)(brow0 + row)*K + k0 + ko);
    }
    __syncthreads();
    #pragma unroll
    for (int q=0;q<4;q++){
      int c = q*256 + tid;
      int row = c >> 3;
      int ko = (c & 7) << 3;
      *(shortx8*)&As[row*72 + ko] = ra[q];
      *(shortx8*)&Bs[row*72 + ko] = rb[q];
    }
    __syncthreads();
    #pragma unroll
    for (int kk=0; kk<2; kk++){
      shortx8 af[4], bfr[4];
      #pragma unroll
      for (int mi=0;mi<4;mi++)
        af[mi] = *(const shortx8*)&As[(wr*64 + mi*16 + (lane&15))*72 + kk*32 + ((lane>>4)<<3)];
      #pragma unroll
      for (int ni=0;ni<4;ni++)
        bfr[ni] = *(const shortx8*)&Bs[(wc*64 + ni*16 + (lane&15))*72 + kk*32 + ((lane>>4)<<3)];
      #pragma unroll
      for (int mi=0;mi<4;mi++)
        #pragma unroll
        for (int ni=0;ni<4;ni++)
          acc[mi][ni] = mfma16x16x32bf(af[mi], bfr[ni], acc[mi][ni]);
    }
  }
  asm volatile("s_nop 7\ns_nop 7\ns_nop 7");   // MFMA->VALU hazard guard

  #pragma unroll
  for (int mi=0;mi<4;mi++){
    #pragma unroll
    for (int j=0;j<4;j++){
      int row = wr*64 + mi*16 + ((lane>>4)<<2) + j;   // C/D: row=(lane>>4)*4+reg  [m89]
      int grow = rowbase + row;
      float rb6[6];
      bool needr = (EPI==0) || ((EPI==5) && blockIdx.y==1);
      if (needr){
        #pragma unroll
        for (int q=0;q<6;q++) rb6[q] = rbfp[grow*6+q];
      }
      #pragma unroll
      for (int ni=0;ni<4;ni++){
        int col = wc*64 + ni*16 + (lane&15);           // C/D: col=lane&15
        float v = acc[mi][ni][j];
        size_t oidx = (size_t)grow*128 + col;
        if (EPI==0){
          float e = bias[col];
          #pragma unroll
          for (int q=0;q<6;q++) e += rb6[q]*W6[q*128+col];
          v = swishf(v + e);
          outF[oidx] = v;
          outB[oidx] = f2bf(v);
        } else if (EPI==4){
          float nm = minp[oidx] + swishf(v + bias[col]);
          outF[oidx] = nm;
          outB[oidx] = f2bf(nm);
        } else { // EPI==5
          if (blockIdx.y == 0){
            v = swishf(v + bias[col]);
            outB[oidx] = f2bf(v);
          } else {
            float rp = 0.f;
            #pragma unroll
            for (int q=0;q<6;q++) rp += rb6[q]*W6[q*128+col];
            v = swishf(v + bias2[col]) * rp;
            outB2[oidx] = f2bf(v);
          }
        }
      }
    }
  }
}

// ---------------- out_layer: wave per atom ----------------
__global__ __launch_bounds__(256)
void out_layer_k(const int* __restrict__ eperm, const int* __restrict__ eoffs,
                 const unsigned short* __restrict__ mbf, const float* __restrict__ rbf,
                 const float* __restrict__ Wrbf, const float* __restrict__ W1,
                 const float* __restrict__ b1, const float* __restrict__ W2,
                 const int* __restrict__ bseg, float* __restrict__ out){
  __shared__ float ta_lds[4][128];
  int lane = threadIdx.x & 63;
  int wv = __builtin_amdgcn_readfirstlane(threadIdx.x >> 6);
  int a = blockIdx.x*4 + wv;
  int f0 = lane*2;
  float wr0[6], wr1[6];
  #pragma unroll
  for (int q=0;q<6;q++){ wr0[q] = Wrbf[q*128+f0]; wr1[q] = Wrbf[q*128+f0+1]; }
  float ta0 = 0.f, ta1 = 0.f;
  int s = eoffs[a], e_ = eoffs[a+1];
  for (int t = s; t < e_; t++){
    int e = eperm[t];
    unsigned mv = *(const unsigned*)&mbf[(size_t)e*128 + f0];
    float r0 = rbf[e*6+0], r1 = rbf[e*6+1], r2 = rbf[e*6+2];
    float r3 = rbf[e*6+3], r4 = rbf[e*6+4], r5 = rbf[e*6+5];
    float rp0 = r0*wr0[0]+r1*wr0[1]+r2*wr0[2]+r3*wr0[3]+r4*wr0[4]+r5*wr0[5];
    float rp1 = r0*wr1[0]+r1*wr1[1]+r2*wr1[2]+r3*wr1[3]+r4*wr1[4]+r5*wr1[5];
    ta0 += bf2f((unsigned short)(mv & 0xffffu))*rp0;
    ta1 += bf2f((unsigned short)(mv >> 16))*rp1;
  }
  ta_lds[wv][f0]   = ta0;
  ta_lds[wv][f0+1] = ta1;
  float p = 0.f;
  #pragma unroll
  for (int h=0; h<2; h++){
    int n = lane + h*64;
    float o = b1[n];
    for (int f=0; f<128; f++) o += ta_lds[wv][f]*W1[f*128+n];
    p += swishf(o)*W2[n];
  }
  #pragma unroll
  for (int off=32; off; off>>=1) p += __shfl_down(p, off);
  if (lane == 0) atomicAdd(&out[bseg[a]], p);
}

// ---------------- launch ----------------
extern "C" void kernel_launch(void* const* d_in, const int* in_sizes, int n_in,
                              void* d_out, int out_size, void* d_ws, size_t ws_size,
                              hipStream_t stream){
  const int*   Z    = (const int*)d_in[0];
  const float* R    = (const float*)d_in[1];
  const int*   bseg = (const int*)d_in[2];
  const int*   ei   = (const int*)d_in[3];
  const int*   ej   = (const int*)d_in[4];
  const int*   texp = (const int*)d_in[5];
  const int*   tred = (const int*)d_in[6];
  const int*   t3i  = (const int*)d_in[7];
  const int*   t3j  = (const int*)d_in[8];
  const int*   t3k  = (const int*)d_in[9];
  const float* emb  = (const float*)d_in[10];
  const float* Wemb = (const float*)d_in[11];
  const float* bemb = (const float*)d_in[12];
  const float* oWr  = (const float*)d_in[13];
  const float* oW1  = (const float*)d_in[14];
  const float* ob1  = (const float*)d_in[15];
  const float* oW2  = (const float*)d_in[16];
  const float* iWr  = (const float*)d_in[17];
  const float* iWs  = (const float*)d_in[18];
  const float* iWkj = (const float*)d_in[19];
  const float* ibkj = (const float*)d_in[20];
  const float* iWji = (const float*)d_in[21];
  const float* ibji = (const float*)d_in[22];
  const float* iWb  = (const float*)d_in[23];
  const float* iWf  = (const float*)d_in[24];
  const float* ibf  = (const float*)d_in[25];
  float* out = (float*)d_out;

  char* p = (char*)d_ws;
  auto alloc = [&](size_t bytes)->char*{ char* r = p; p += (bytes + 255) & ~(size_t)255; return r; };
  float* Dij    = (float*)alloc((size_t)NEc*4);
  float* rbf    = (float*)alloc((size_t)NEc*6*4);
  float* angp   = (float*)alloc((size_t)NTc*16*4);
  float* sball  = (float*)alloc((size_t)NTc*8*4);
  float* m      = (float*)alloc((size_t)NEc*128*4);
  unsigned short* mbf  = (unsigned short*)alloc((size_t)NEc*128*2);
  unsigned short* xji  = (unsigned short*)alloc((size_t)NEc*128*2);
  unsigned short* xkj  = (unsigned short*)alloc((size_t)NEc*128*2);
  unsigned short* afin = (unsigned short*)alloc((size_t)NEc*128*2);
  int* thist = (int*)alloc((size_t)NEc*4);
  int* toffs = (int*)alloc((size_t)(NEc+1)*4);
  int* tperm = (int*)alloc((size_t)NTc*4);
  int* tmeta = (int*)alloc((size_t)NTc*4);
  int* ehist = (int*)alloc((size_t)NAc*4);
  int* eoffs = (int*)alloc((size_t)(NAc+1)*4);
  int* eperm = (int*)alloc((size_t)NEc*4);
  int* bsum  = (int*)alloc((size_t)257*4);
  unsigned short* embbf = (unsigned short*)alloc((size_t)95*128*2);
  unsigned short* W12et = (unsigned short*)alloc((size_t)128*256*2);
  unsigned short* Wjkt  = (unsigned short*)alloc((size_t)7*32768*2);
  unsigned short* Wfint = (unsigned short*)alloc((size_t)7*16384*2);
  unsigned short* Wbilt = (unsigned short*)alloc((size_t)7*131072*2);

  hipMemsetAsync(d_out, 0, 64*sizeof(float), stream);
  hipMemsetAsync(thist, 0, (size_t)NEc*4, stream);
  hipMemsetAsync(ehist, 0, (size_t)NAc*4, stream);

  prep_transpose<<<dim3(128,22),256,0,stream>>>(Wemb, iWji, iWkj, iWf, W12et, Wjkt, Wfint);
  prep_wbil<<<3584,256,0,stream>>>(iWb, Wbilt);
  prep_emb<<<48,256,0,stream>>>(emb, embbf);
  egeom_k<<<NEc/256,256,0,stream>>>(R, ei, ej, Dij, rbf);

  // triplet sort by id_reduce_ji
  hist_k<<<512,256,0,stream>>>(tred, NTc, thist);
  scan1_k<<<NEc/256,256,0,stream>>>(thist, toffs, bsum);
  scan2_k<<<1,256,0,stream>>>(bsum, NEc/256);
  scan3_k<<<NEc/256,256,0,stream>>>(thist, toffs, bsum, NEc);
  hipMemsetAsync(thist, 0, (size_t)NEc*4, stream);
  scatter_k<<<512,256,0,stream>>>(tred, NTc, toffs, thist, tperm);
  // edge sort by idnb_i
  hist_k<<<256,256,0,stream>>>(ei, NEc, ehist);
  scan1_k<<<NAc/256,256,0,stream>>>(ehist, eoffs, bsum);
  scan2_k<<<1,256,0,stream>>>(bsum, NAc/256);
  scan3_k<<<NAc/256,256,0,stream>>>(ehist, eoffs, bsum, NAc);
  hipMemsetAsync(ehist, 0, (size_t)NAc*4, stream);
  scatter_k<<<256,256,0,stream>>>(ei, NEc, eoffs, ehist, eperm);

  // sorted-order triplet geometry
  tgeom_k<<<NTc/256,256,0,stream>>>(R, t3i, t3j, t3k, texp, tperm, Dij, angp, tmeta);

  // m0 = swish([h_i,h_j,rbf] @ W_emb + b)
  gemm_k<1,0><<<NEc/128,256,0,stream>>>(embbf, W12et, 256, 0, 0, ei, ej, Z,
      rbf, Wemb + 256*128, bemb, nullptr, nullptr, nullptr, m, mbf, nullptr);
  out_layer_k<<<NAc/4,256,0,stream>>>(eperm, eoffs, mbf, rbf,
                                      oWr, oW1, ob1, oW2, bseg, out);

  for (int i=0;i<7;i++){
    sb_k<<<NTc/256,256,0,stream>>>(angp, iWs + i*392, sball);
    // dual GEMM: y=0 -> xji, y=1 -> xkj
    gemm_k<0,5><<<dim3(NEc/128,2),256,0,stream>>>(mbf, Wjkt + i*32768, 128, 0, 0,
        nullptr, nullptr, nullptr, rbf, iWr + i*768, ibji + i*128, ibkj + i*128,
        nullptr, nullptr, nullptr, xji, xkj);
    // fused G-build + bilinear GEMM + xji add -> afin (v2: 16 edges/block)
    bilin_k<<<NEc/16,256,0,stream>>>(toffs, tmeta, sball, xkj,
                                     Wbilt + (size_t)i*131072, xji, afin);
    gemm_k<0,4><<<NEc/128,256,0,stream>>>(afin, Wfint + i*16384, 128, 0, 0,
        nullptr, nullptr, nullptr, nullptr, nullptr, ibf + i*128, nullptr,
        m, nullptr, m, mbf, nullptr);
    out_layer_k<<<NAc/4,256,0,stream>>>(eperm, eoffs, mbf, rbf,
        oWr + (i+1)*768, oW1 + (i+1)*16384, ob1 + (i+1)*128, oW2 + (i+1)*128, bseg, out);
  }
  (void)in_sizes; (void)n_in; (void)out_size;
}

// Round 11
// 1708.270 us; speedup vs baseline: 1.2180x; 1.2180x over previous
//
#include <hip/hip_runtime.h>

typedef __attribute__((ext_vector_type(8))) short shortx8;
typedef __attribute__((ext_vector_type(4))) float floatx4;
typedef __attribute__((ext_vector_type(4))) unsigned uintx4;

constexpr int NAc = 4096;     // atoms
constexpr int NEc = 65536;    // edges
constexpr int NTc = 262144;   // triplets
constexpr float PI_F = 3.14159265358979323846f;
constexpr float SQ25 = 0.63245553203367587f;   // sqrt(2/5)

__device__ __forceinline__ float bf2f(unsigned short h){ return __uint_as_float(((unsigned)h)<<16); }
__device__ __forceinline__ unsigned short f2bf(float f){
  unsigned u = __float_as_uint(f);
  u += 0x7fffu + ((u>>16)&1u);
  return (unsigned short)(u>>16);
}
__device__ __forceinline__ float swishf(float x){ return x/(1.f+__expf(-x)); }

__device__ __forceinline__ floatx4 mfma16x16x32bf(shortx8 a, shortx8 b, floatx4 c){
  floatx4 d;
  asm("v_mfma_f32_16x16x32_bf16 %0, %1, %2, %3" : "=v"(d) : "v"(a), "v"(b), "v"(c));
  return d;
}

// ---------------- geometry ----------------
__global__ __launch_bounds__(256)
void egeom_k(const float* __restrict__ R, const int* __restrict__ ei,
             const int* __restrict__ ej, float* __restrict__ Dij, float* __restrict__ rbf){
  int e = blockIdx.x*256 + threadIdx.x;
  int i = ei[e], j = ej[e];
  float dx = R[i*3+0]-R[j*3+0];
  float dy = R[i*3+1]-R[j*3+1];
  float dz = R[i*3+2]-R[j*3+2];
  float d2 = dx*dx+dy*dy+dz*dz;
  float D = sqrtf(fmaxf(d2, 0.f));
  Dij[e] = D;
  float d = fmaxf(D, 1e-6f);
  float s = PI_F*d*0.2f;
  float sn, cs; sincosf(s, &sn, &cs);
  float invd = SQ25/d;
  float sprev = 0.f, scur = sn;
  #pragma unroll
  for (int q=0;q<6;q++){
    rbf[e*6+q] = scur*invd;
    float nx = 2.f*cs*scur - sprev; sprev = scur; scur = nx;
  }
}

// sorted-order triplet geometry: thread p handles w = tperm[p].
// Writes angp[p][16] AoS (coalesced) + tmeta[p] = texp[w].
__global__ __launch_bounds__(256)
void tgeom_k(const float* __restrict__ R, const int* __restrict__ t3i,
             const int* __restrict__ t3j, const int* __restrict__ t3k,
             const int* __restrict__ texp, const int* __restrict__ tperm,
             const float* __restrict__ Dij, float* __restrict__ angp,
             int* __restrict__ tmeta){
  int p = blockIdx.x*256 + threadIdx.x;
  int w = tperm[p];
  int ia = t3i[w], ja = t3j[w], ka = t3k[w];
  int e  = texp[w];
  tmeta[p] = e;
  float xi = R[ia*3+0], yi = R[ia*3+1], zi = R[ia*3+2];
  float r1x = R[ja*3+0]-xi, r1y = R[ja*3+1]-yi, r1z = R[ja*3+2]-zi;
  float r2x = R[ka*3+0]-xi, r2y = R[ka*3+1]-yi, r2z = R[ka*3+2]-zi;
  float dt = r1x*r2x + r1y*r2y + r1z*r2z;
  float cx = r1y*r2z - r1z*r2y;
  float cy = r1z*r2x - r1x*r2z;
  float cz = r1x*r2y - r1y*r2x;
  float yv = sqrtf(cx*cx + cy*cy + cz*cz);
  float h = sqrtf(dt*dt + yv*yv);
  float c1 = (h > 0.f) ? dt/h : 1.f;   // cos(atan2(y,x))
  float f[16];
  f[0] = 1.f; f[1] = c1;
  float cprev = 1.f, ccur = c1;
  #pragma unroll
  for (int l=2;l<7;l++){
    float nx = 2.f*c1*ccur - cprev; cprev = ccur; ccur = nx;
    f[l] = nx;
  }
  float d = fmaxf(Dij[e], 1e-6f);
  float s = PI_F*d*0.2f;
  float sn, cs; sincosf(s, &sn, &cs);
  float invd = 1.f/d;
  float sprev = 0.f, scur = sn;
  #pragma unroll
  for (int q=0;q<7;q++){
    f[7+q] = scur*invd;
    float nx = 2.f*cs*scur - sprev; sprev = scur; scur = nx;
  }
  f[14] = 0.f; f[15] = 0.f;
  float4* op = (float4*)(angp + (size_t)p*16);
  op[0] = (float4){f[0],f[1],f[2],f[3]};
  op[1] = (float4){f[4],f[5],f[6],f[7]};
  op[2] = (float4){f[8],f[9],f[10],f[11]};
  op[3] = (float4){f[12],f[13],f[14],f[15]};
}

// ---------------- weight prep (fp32 -> bf16, transpose to [N,K]) ----------------
// Wjk: concat [ji rows 0..127 | kj rows 128..255] per layer
__global__ __launch_bounds__(256)
void prep_transpose(const float* __restrict__ Wemb, const float* __restrict__ Wji,
                    const float* __restrict__ Wkj, const float* __restrict__ Wfin,
                    unsigned short* __restrict__ dW12, unsigned short* __restrict__ dWjk,
                    unsigned short* __restrict__ dWfin){
  int y = blockIdx.y;
  int x = blockIdx.x*256 + threadIdx.x;
  if (y == 0){
    if (x < 32768){
      int n = x >> 8, k = x & 255;
      dW12[x] = f2bf(Wemb[k*128 + n]);
    }
  } else {
    if (x < 16384){
      int n = x >> 7, k = x & 127;
      const float* s; unsigned short* d;
      if (y <= 7)      { s = Wji  + (y-1)*16384;  d = dWjk  + (y-1)*32768; }
      else if (y <= 14){ s = Wkj  + (y-8)*16384;  d = dWjk  + (y-8)*32768 + 16384; }
      else             { s = Wfin + (y-15)*16384; d = dWfin + (y-15)*16384; }
      d[x] = f2bf(s[k*128 + n]);
    }
  }
}

// Wbil [j,l,i] -> Wbilt [i][k=(j*8+l)]  (plain [1024,128] transpose per layer)
__global__ __launch_bounds__(256)
void prep_wbil(const float* __restrict__ Wbil, unsigned short* __restrict__ dst){
  int x = blockIdx.x*256 + threadIdx.x;
  if (x < 7*131072){
    int i = x >> 17; int rem = x & 131071;
    int o = rem >> 10; int k = rem & 1023;
    dst[x] = f2bf(Wbil[(size_t)i*131072 + (size_t)k*128 + o]);
  }
}

__global__ __launch_bounds__(256)
void prep_emb(const float* __restrict__ emb, unsigned short* __restrict__ d){
  int x = blockIdx.x*256 + threadIdx.x;
  if (x < 95*128) d[x] = f2bf(emb[x]);
}

// ---------------- counting sort ----------------
__global__ __launch_bounds__(256)
void hist_k(const int* __restrict__ ids, int n, int* __restrict__ hist){
  int stride = gridDim.x*blockDim.x;
  for (int x = blockIdx.x*blockDim.x + threadIdx.x; x < n; x += stride)
    atomicAdd(&hist[ids[x]], 1);
}

// hierarchical scan: nbins <= 65536, nbins % 256 == 0, nbins/256 <= 256
__global__ __launch_bounds__(256)
void scan1_k(const int* __restrict__ hist, int* __restrict__ offs, int* __restrict__ bsum){
  __shared__ int buf[256];
  int t = threadIdx.x;
  int x = blockIdx.x*256 + t;
  int v = hist[x];
  buf[t] = v; __syncthreads();
  #pragma unroll
  for (int d=1; d<256; d<<=1){
    int u = (t>=d) ? buf[t-d] : 0;
    __syncthreads(); buf[t] += u; __syncthreads();
  }
  offs[x] = buf[t] - v;                 // exclusive within block
  if (t == 255) bsum[blockIdx.x] = buf[255];
}

__global__ __launch_bounds__(256)
void scan2_k(int* __restrict__ bsum, int nb){
  __shared__ int buf[256];
  int t = threadIdx.x;
  int v = (t < nb) ? bsum[t] : 0;
  buf[t] = v; __syncthreads();
  #pragma unroll
  for (int d=1; d<256; d<<=1){
    int u = (t>=d) ? buf[t-d] : 0;
    __syncthreads(); buf[t] += u; __syncthreads();
  }
  if (t < nb) bsum[t] = buf[t] - v;     // exclusive
}

__global__ __launch_bounds__(256)
void scan3_k(const int* __restrict__ hist, int* __restrict__ offs,
             const int* __restrict__ bsum, int nbins){
  int x = blockIdx.x*256 + threadIdx.x;
  int o = offs[x] + bsum[blockIdx.x];
  offs[x] = o;
  if (x == nbins-1) offs[nbins] = o + hist[x];
}

__global__ __launch_bounds__(256)
void scatter_k(const int* __restrict__ ids, int n, const int* __restrict__ offs,
               int* __restrict__ cursor, int* __restrict__ perm){
  int stride = gridDim.x*blockDim.x;
  for (int x = blockIdx.x*blockDim.x + threadIdx.x; x < n; x += stride){
    int b = ids[x];
    int pos = offs[b] + atomicAdd(&cursor[b], 1);
    perm[pos] = x;
  }
}

// ---------------- sb = sbf @ Wsbf[i]  [T,8] (sorted order, streaming) ----------------
__global__ __launch_bounds__(256)
void sb_k(const float* __restrict__ angp, const float* __restrict__ Wsbf,
          float* __restrict__ sb){
  __shared__ float Ws[392];
  for (int x = threadIdx.x; x < 392; x += 256) Ws[x] = Wsbf[x];
  __syncthreads();
  int p = blockIdx.x*256 + threadIdx.x;
  const float4* ap = (const float4*)(angp + (size_t)p*16);
  float4 a0 = ap[0], a1 = ap[1], a2 = ap[2], a3 = ap[3];
  float ca[7] = {a0.x,a0.y,a0.z,a0.w,a1.x,a1.y,a1.z};
  float rd[7] = {a1.w,a2.x,a2.y,a2.z,a2.w,a3.x,a3.y};
  float o[8] = {0,0,0,0,0,0,0,0};
  #pragma unroll
  for (int a=0;a<7;a++){
    #pragma unroll
    for (int r=0;r<7;r++){
      float pr = ca[a]*rd[r];
      const float* wp = &Ws[(a*7+r)*8];
      #pragma unroll
      for (int l=0;l<8;l++) o[l] += pr*wp[l];
    }
  }
  float4* op = (float4*)(sb + (size_t)p*8);
  op[0] = (float4){o[0],o[1],o[2],o[3]};
  op[1] = (float4){o[4],o[5],o[6],o[7]};
}

// ---------------- G[r, j*8+l] = sum_{w in r} sb[w,l]*xkj[exp[w],j]  (wave/edge, 4-deep MLP) ----------------
// R10 post-mortem: fused bilin was MLP-starved (1 gather in flight/wave -> 429 GB/s).
// Split version at 0 LDS -> 32 waves/CU, and 4-deep batched gathers -> 4x outstanding.
__global__ __launch_bounds__(256)
void gbuild_k(int c0, const int* __restrict__ toffs, const int* __restrict__ tmeta,
              const float* __restrict__ sb, const unsigned short* __restrict__ xkj,
              unsigned short* __restrict__ G){
  int lane = threadIdx.x & 63;
  int wv = __builtin_amdgcn_readfirstlane(threadIdx.x >> 6);
  int r = c0 + blockIdx.x*4 + wv;
  float acc0[8] = {}, acc1[8] = {};
  int s = toffs[r], e_ = toffs[r+1];
  for (int t = s; t < e_; t += 4){
    int tl = e_ - 1;
    int t1 = (t+1 < e_) ? t+1 : tl;
    int t2 = (t+2 < e_) ? t+2 : tl;
    int t3 = (t+3 < e_) ? t+3 : tl;
    float w1 = (t+1 < e_) ? 1.f : 0.f;
    float w2 = (t+2 < e_) ? 1.f : 0.f;
    float w3 = (t+3 < e_) ? 1.f : 0.f;
    int e0 = tmeta[t], e1 = tmeta[t1], e2 = tmeta[t2], e3 = tmeta[t3];
    // 4 independent row-gathers issued back-to-back -> 4x memory-level parallelism
    unsigned xv0 = *(const unsigned*)&xkj[(size_t)e0*128 + lane*2];
    unsigned xv1 = *(const unsigned*)&xkj[(size_t)e1*128 + lane*2];
    unsigned xv2 = *(const unsigned*)&xkj[(size_t)e2*128 + lane*2];
    unsigned xv3 = *(const unsigned*)&xkj[(size_t)e3*128 + lane*2];
    float4 sa0 = *(const float4*)&sb[(size_t)t *8];
    float4 sc0 = *(const float4*)&sb[(size_t)t *8 + 4];
    float4 sa1 = *(const float4*)&sb[(size_t)t1*8];
    float4 sc1 = *(const float4*)&sb[(size_t)t1*8 + 4];
    float4 sa2 = *(const float4*)&sb[(size_t)t2*8];
    float4 sc2 = *(const float4*)&sb[(size_t)t2*8 + 4];
    float4 sa3 = *(const float4*)&sb[(size_t)t3*8];
    float4 sc3 = *(const float4*)&sb[(size_t)t3*8 + 4];
    float x00 = bf2f((unsigned short)(xv0 & 0xffffu));
    float x01 = bf2f((unsigned short)(xv0 >> 16));
    float x10 = bf2f((unsigned short)(xv1 & 0xffffu)) * w1;
    float x11 = bf2f((unsigned short)(xv1 >> 16)) * w1;
    float x20 = bf2f((unsigned short)(xv2 & 0xffffu)) * w2;
    float x21 = bf2f((unsigned short)(xv2 >> 16)) * w2;
    float x30 = bf2f((unsigned short)(xv3 & 0xffffu)) * w3;
    float x31 = bf2f((unsigned short)(xv3 >> 16)) * w3;
    acc0[0] += sa0.x*x00 + sa1.x*x10 + sa2.x*x20 + sa3.x*x30;
    acc1[0] += sa0.x*x01 + sa1.x*x11 + sa2.x*x21 + sa3.x*x31;
    acc0[1] += sa0.y*x00 + sa1.y*x10 + sa2.y*x20 + sa3.y*x30;
    acc1[1] += sa0.y*x01 + sa1.y*x11 + sa2.y*x21 + sa3.y*x31;
    acc0[2] += sa0.z*x00 + sa1.z*x10 + sa2.z*x20 + sa3.z*x30;
    acc1[2] += sa0.z*x01 + sa1.z*x11 + sa2.z*x21 + sa3.z*x31;
    acc0[3] += sa0.w*x00 + sa1.w*x10 + sa2.w*x20 + sa3.w*x30;
    acc1[3] += sa0.w*x01 + sa1.w*x11 + sa2.w*x21 + sa3.w*x31;
    acc0[4] += sc0.x*x00 + sc1.x*x10 + sc2.x*x20 + sc3.x*x30;
    acc1[4] += sc0.x*x01 + sc1.x*x11 + sc2.x*x21 + sc3.x*x31;
    acc0[5] += sc0.y*x00 + sc1.y*x10 + sc2.y*x20 + sc3.y*x30;
    acc1[5] += sc0.y*x01 + sc1.y*x11 + sc2.y*x21 + sc3.y*x31;
    acc0[6] += sc0.z*x00 + sc1.z*x10 + sc2.z*x20 + sc3.z*x30;
    acc1[6] += sc0.z*x01 + sc1.z*x11 + sc2.z*x21 + sc3.z*x31;
    acc0[7] += sc0.w*x00 + sc1.w*x10 + sc2.w*x20 + sc3.w*x30;
    acc1[7] += sc0.w*x01 + sc1.w*x11 + sc2.w*x21 + sc3.w*x31;
  }
  // layout: G[r_local*1024 + j*8 + l]; lane owns j0=2*lane, j0+1 -> 32B contiguous
  size_t base = (size_t)(r - c0)*1024 + (size_t)lane*16;
  uintx4 v0, v1;
  #pragma unroll
  for (int d=0; d<4; d++){
    v0[d] = (unsigned)f2bf(acc0[2*d]) | ((unsigned)f2bf(acc0[2*d+1]) << 16);
    v1[d] = (unsigned)f2bf(acc1[2*d]) | ((unsigned)f2bf(acc1[2*d+1]) << 16);
  }
  *(uintx4*)&G[base]     = v0;
  *(uintx4*)&G[base + 8] = v1;
}

// ---------------- generic MFMA GEMM: C[M,128] = A[M,K] @ Bt[128,K]^T ----------------
// MODE 0: A direct bf16 [rows, K]. MODE 1: embedding gather.
// EPI 0: m0 = swish(acc + b + rbf@Wemb_tail) -> outF(m f32) + outB(m bf16)
// EPI 3: acc + xji -> outB (afin)
// EPI 4: m += swish(acc + bias) -> outF(m) + outB(m bf16)
// EPI 5: dual (grid.y): y0 -> swish(acc+bias) -> outB (xji); y1 -> swish(acc+bias2)*(rbf@W6) -> outB2 (xkj)
template<int MODE, int EPI>
__global__ __launch_bounds__(256)
void gemm_k(const unsigned short* __restrict__ A, const unsigned short* __restrict__ Bt,
            int K, int rowoff, int arow0,
            const int* __restrict__ gi, const int* __restrict__ gj, const int* __restrict__ Zr,
            const float* __restrict__ rbfp, const float* __restrict__ W6,
            const float* __restrict__ bias, const float* __restrict__ bias2,
            const float* minp, const unsigned short* __restrict__ xjip,
            float* outF, unsigned short* outB, unsigned short* outB2){
  __shared__ __align__(16) unsigned short As[128*72];
  __shared__ __align__(16) unsigned short Bs[128*72];
  const int tid = threadIdx.x;
  const int lane = tid & 63;
  const int wid = tid >> 6;
  const int wr = wid >> 1, wc = wid & 1;
  const int rowbase = rowoff + blockIdx.x*128;
  const int brow0 = (EPI==5) ? (int)blockIdx.y*128 : 0;
  floatx4 acc[4][4];
  #pragma unroll
  for (int i=0;i<4;i++)
    #pragma unroll
    for (int j=0;j<4;j++) acc[i][j] = (floatx4){0.f,0.f,0.f,0.f};

  for (int k0 = 0; k0 < K; k0 += 64){
    shortx8 ra[4], rb[4];
    #pragma unroll
    for (int q=0;q<4;q++){
      int c = q*256 + tid;
      int row = c >> 3;
      int ko = (c & 7) << 3;
      const unsigned short* asrc;
      if (MODE == 0){
        asrc = A + (size_t)(rowbase - arow0 + row)*K + k0 + ko;
      } else {
        int grow = rowbase + row;
        int kg = k0 + ko;
        int atom = (kg < 128) ? gi[grow] : gj[grow];
        asrc = A + (size_t)Zr[atom]*128 + (kg & 127);
      }
      ra[q] = *(const shortx8*)asrc;
      rb[q] = *(const shortx8*)(Bt + (size_t)(brow0 + row)*K + k0 + ko);
    }
    __syncthreads();
    #pragma unroll
    for (int q=0;q<4;q++){
      int c = q*256 + tid;
      int row = c >> 3;
      int ko = (c & 7) << 3;
      *(shortx8*)&As[row*72 + ko] = ra[q];
      *(shortx8*)&Bs[row*72 + ko] = rb[q];
    }
    __syncthreads();
    #pragma unroll
    for (int kk=0; kk<2; kk++){
      shortx8 af[4], bfr[4];
      #pragma unroll
      for (int mi=0;mi<4;mi++)
        af[mi] = *(const shortx8*)&As[(wr*64 + mi*16 + (lane&15))*72 + kk*32 + ((lane>>4)<<3)];
      #pragma unroll
      for (int ni=0;ni<4;ni++)
        bfr[ni] = *(const shortx8*)&Bs[(wc*64 + ni*16 + (lane&15))*72 + kk*32 + ((lane>>4)<<3)];
      #pragma unroll
      for (int mi=0;mi<4;mi++)
        #pragma unroll
        for (int ni=0;ni<4;ni++)
          acc[mi][ni] = mfma16x16x32bf(af[mi], bfr[ni], acc[mi][ni]);
    }
  }
  asm volatile("s_nop 7\ns_nop 7\ns_nop 7");   // MFMA->VALU hazard guard

  #pragma unroll
  for (int mi=0;mi<4;mi++){
    #pragma unroll
    for (int j=0;j<4;j++){
      int row = wr*64 + mi*16 + ((lane>>4)<<2) + j;   // C/D: row=(lane>>4)*4+reg  [m89]
      int grow = rowbase + row;
      float rb6[6];
      bool needr = (EPI==0) || ((EPI==5) && blockIdx.y==1);
      if (needr){
        #pragma unroll
        for (int q=0;q<6;q++) rb6[q] = rbfp[grow*6+q];
      }
      #pragma unroll
      for (int ni=0;ni<4;ni++){
        int col = wc*64 + ni*16 + (lane&15);           // C/D: col=lane&15
        float v = acc[mi][ni][j];
        size_t oidx = (size_t)grow*128 + col;
        if (EPI==0){
          float e = bias[col];
          #pragma unroll
          for (int q=0;q<6;q++) e += rb6[q]*W6[q*128+col];
          v = swishf(v + e);
          outF[oidx] = v;
          outB[oidx] = f2bf(v);
        } else if (EPI==3){
          v += bf2f(xjip[oidx]);
          outB[oidx] = f2bf(v);
        } else if (EPI==4){
          float nm = minp[oidx] + swishf(v + bias[col]);
          outF[oidx] = nm;
          outB[oidx] = f2bf(nm);
        } else { // EPI==5
          if (blockIdx.y == 0){
            v = swishf(v + bias[col]);
            outB[oidx] = f2bf(v);
          } else {
            float rp = 0.f;
            #pragma unroll
            for (int q=0;q<6;q++) rp += rb6[q]*W6[q*128+col];
            v = swishf(v + bias2[col]) * rp;
            outB2[oidx] = f2bf(v);
          }
        }
      }
    }
  }
}

// ---------------- out_layer: wave per atom ----------------
__global__ __launch_bounds__(256)
void out_layer_k(const int* __restrict__ eperm, const int* __restrict__ eoffs,
                 const unsigned short* __restrict__ mbf, const float* __restrict__ rbf,
                 const float* __restrict__ Wrbf, const float* __restrict__ W1,
                 const float* __restrict__ b1, const float* __restrict__ W2,
                 const int* __restrict__ bseg, float* __restrict__ out){
  __shared__ float ta_lds[4][128];
  int lane = threadIdx.x & 63;
  int wv = __builtin_amdgcn_readfirstlane(threadIdx.x >> 6);
  int a = blockIdx.x*4 + wv;
  int f0 = lane*2;
  float wr0[6], wr1[6];
  #pragma unroll
  for (int q=0;q<6;q++){ wr0[q] = Wrbf[q*128+f0]; wr1[q] = Wrbf[q*128+f0+1]; }
  float ta0 = 0.f, ta1 = 0.f;
  int s = eoffs[a], e_ = eoffs[a+1];
  for (int t = s; t < e_; t++){
    int e = eperm[t];
    unsigned mv = *(const unsigned*)&mbf[(size_t)e*128 + f0];
    float r0 = rbf[e*6+0], r1 = rbf[e*6+1], r2 = rbf[e*6+2];
    float r3 = rbf[e*6+3], r4 = rbf[e*6+4], r5 = rbf[e*6+5];
    float rp0 = r0*wr0[0]+r1*wr0[1]+r2*wr0[2]+r3*wr0[3]+r4*wr0[4]+r5*wr0[5];
    float rp1 = r0*wr1[0]+r1*wr1[1]+r2*wr1[2]+r3*wr1[3]+r4*wr1[4]+r5*wr1[5];
    ta0 += bf2f((unsigned short)(mv & 0xffffu))*rp0;
    ta1 += bf2f((unsigned short)(mv >> 16))*rp1;
  }
  ta_lds[wv][f0]   = ta0;
  ta_lds[wv][f0+1] = ta1;
  float p = 0.f;
  #pragma unroll
  for (int h=0; h<2; h++){
    int n = lane + h*64;
    float o = b1[n];
    for (int f=0; f<128; f++) o += ta_lds[wv][f]*W1[f*128+n];
    p += swishf(o)*W2[n];
  }
  #pragma unroll
  for (int off=32; off; off>>=1) p += __shfl_down(p, off);
  if (lane == 0) atomicAdd(&out[bseg[a]], p);
}

// ---------------- launch ----------------
extern "C" void kernel_launch(void* const* d_in, const int* in_sizes, int n_in,
                              void* d_out, int out_size, void* d_ws, size_t ws_size,
                              hipStream_t stream){
  const int*   Z    = (const int*)d_in[0];
  const float* R    = (const float*)d_in[1];
  const int*   bseg = (const int*)d_in[2];
  const int*   ei   = (const int*)d_in[3];
  const int*   ej   = (const int*)d_in[4];
  const int*   texp = (const int*)d_in[5];
  const int*   tred = (const int*)d_in[6];
  const int*   t3i  = (const int*)d_in[7];
  const int*   t3j  = (const int*)d_in[8];
  const int*   t3k  = (const int*)d_in[9];
  const float* emb  = (const float*)d_in[10];
  const float* Wemb = (const float*)d_in[11];
  const float* bemb = (const float*)d_in[12];
  const float* oWr  = (const float*)d_in[13];
  const float* oW1  = (const float*)d_in[14];
  const float* ob1  = (const float*)d_in[15];
  const float* oW2  = (const float*)d_in[16];
  const float* iWr  = (const float*)d_in[17];
  const float* iWs  = (const float*)d_in[18];
  const float* iWkj = (const float*)d_in[19];
  const float* ibkj = (const float*)d_in[20];
  const float* iWji = (const float*)d_in[21];
  const float* ibji = (const float*)d_in[22];
  const float* iWb  = (const float*)d_in[23];
  const float* iWf  = (const float*)d_in[24];
  const float* ibf  = (const float*)d_in[25];
  float* out = (float*)d_out;

  char* p = (char*)d_ws;
  auto alloc = [&](size_t bytes)->char*{ char* r = p; p += (bytes + 255) & ~(size_t)255; return r; };
  float* Dij    = (float*)alloc((size_t)NEc*4);
  float* rbf    = (float*)alloc((size_t)NEc*6*4);
  float* angp   = (float*)alloc((size_t)NTc*16*4);
  float* sball  = (float*)alloc((size_t)NTc*8*4);
  float* m      = (float*)alloc((size_t)NEc*128*4);
  unsigned short* mbf  = (unsigned short*)alloc((size_t)NEc*128*2);
  unsigned short* xji  = (unsigned short*)alloc((size_t)NEc*128*2);
  unsigned short* xkj  = (unsigned short*)alloc((size_t)NEc*128*2);
  unsigned short* afin = (unsigned short*)alloc((size_t)NEc*128*2);
  int* thist = (int*)alloc((size_t)NEc*4);
  int* toffs = (int*)alloc((size_t)(NEc+1)*4);
  int* tperm = (int*)alloc((size_t)NTc*4);
  int* tmeta = (int*)alloc((size_t)NTc*4);
  int* ehist = (int*)alloc((size_t)NAc*4);
  int* eoffs = (int*)alloc((size_t)(NAc+1)*4);
  int* eperm = (int*)alloc((size_t)NEc*4);
  int* bsum  = (int*)alloc((size_t)257*4);
  unsigned short* embbf = (unsigned short*)alloc((size_t)95*128*2);
  unsigned short* W12et = (unsigned short*)alloc((size_t)128*256*2);
  unsigned short* Wjkt  = (unsigned short*)alloc((size_t)7*32768*2);
  unsigned short* Wfint = (unsigned short*)alloc((size_t)7*16384*2);
  unsigned short* Wbilt = (unsigned short*)alloc((size_t)7*131072*2);
  size_t fixed = (size_t)(p - (char*)d_ws);

  // choose G chunking to fit workspace
  int nch = 1;
  while (nch < 8 && fixed + ((size_t)NEc/nch)*1024*2 > ws_size) nch <<= 1;
  int ECH = NEc / nch;
  unsigned short* Gbuf = (unsigned short*)alloc((size_t)ECH*1024*2);

  hipMemsetAsync(d_out, 0, 64*sizeof(float), stream);
  hipMemsetAsync(thist, 0, (size_t)NEc*4, stream);
  hipMemsetAsync(ehist, 0, (size_t)NAc*4, stream);

  prep_transpose<<<dim3(128,22),256,0,stream>>>(Wemb, iWji, iWkj, iWf, W12et, Wjkt, Wfint);
  prep_wbil<<<3584,256,0,stream>>>(iWb, Wbilt);
  prep_emb<<<48,256,0,stream>>>(emb, embbf);
  egeom_k<<<NEc/256,256,0,stream>>>(R, ei, ej, Dij, rbf);

  // triplet sort by id_reduce_ji
  hist_k<<<512,256,0,stream>>>(tred, NTc, thist);
  scan1_k<<<NEc/256,256,0,stream>>>(thist, toffs, bsum);
  scan2_k<<<1,256,0,stream>>>(bsum, NEc/256);
  scan3_k<<<NEc/256,256,0,stream>>>(thist, toffs, bsum, NEc);
  hipMemsetAsync(thist, 0, (size_t)NEc*4, stream);
  scatter_k<<<512,256,0,stream>>>(tred, NTc, toffs, thist, tperm);
  // edge sort by idnb_i
  hist_k<<<256,256,0,stream>>>(ei, NEc, ehist);
  scan1_k<<<NAc/256,256,0,stream>>>(ehist, eoffs, bsum);
  scan2_k<<<1,256,0,stream>>>(bsum, NAc/256);
  scan3_k<<<NAc/256,256,0,stream>>>(ehist, eoffs, bsum, NAc);
  hipMemsetAsync(ehist, 0, (size_t)NAc*4, stream);
  scatter_k<<<256,256,0,stream>>>(ei, NEc, eoffs, ehist, eperm);

  // sorted-order triplet geometry
  tgeom_k<<<NTc/256,256,0,stream>>>(R, t3i, t3j, t3k, texp, tperm, Dij, angp, tmeta);

  // m0 = swish([h_i,h_j,rbf] @ W_emb + b)
  gemm_k<1,0><<<NEc/128,256,0,stream>>>(embbf, W12et, 256, 0, 0, ei, ej, Z,
      rbf, Wemb + 256*128, bemb, nullptr, nullptr, nullptr, m, mbf, nullptr);
  out_layer_k<<<NAc/4,256,0,stream>>>(eperm, eoffs, mbf, rbf,
                                      oWr, oW1, ob1, oW2, bseg, out);

  for (int i=0;i<7;i++){
    sb_k<<<NTc/256,256,0,stream>>>(angp, iWs + i*392, sball);
    // dual GEMM: y=0 -> xji, y=1 -> xkj
    gemm_k<0,5><<<dim3(NEc/128,2),256,0,stream>>>(mbf, Wjkt + i*32768, 128, 0, 0,
        nullptr, nullptr, nullptr, rbf, iWr + i*768, ibji + i*128, ibkj + i*128,
        nullptr, nullptr, nullptr, xji, xkj);
    for (int c=0;c<nch;c++){
      int c0 = c*ECH;
      gbuild_k<<<ECH/4,256,0,stream>>>(c0, toffs, tmeta, sball, xkj, Gbuf);
      gemm_k<0,3><<<ECH/128,256,0,stream>>>(Gbuf, Wbilt + (size_t)i*131072, 1024, c0, c0,
          nullptr, nullptr, nullptr, nullptr, nullptr, nullptr, nullptr, nullptr,
          xji, nullptr, afin, nullptr);
    }
    gemm_k<0,4><<<NEc/128,256,0,stream>>>(afin, Wfint + i*16384, 128, 0, 0,
        nullptr, nullptr, nullptr, nullptr, nullptr, ibf + i*128, nullptr,
        m, nullptr, m, mbf, nullptr);
    out_layer_k<<<NAc/4,256,0,stream>>>(eperm, eoffs, mbf, rbf,
        oWr + (i+1)*768, oW1 + (i+1)*16384, ob1 + (i+1)*128, oW2 + (i+1)*128, bseg, out);
  }
  (void)in_sizes; (void)n_in; (void)out_size;
}

// Round 12
// 1450.162 us; speedup vs baseline: 1.4347x; 1.1780x over previous
//
#include <hip/hip_runtime.h>

typedef __attribute__((ext_vector_type(8))) short shortx8;
typedef __attribute__((ext_vector_type(4))) float floatx4;
typedef __attribute__((ext_vector_type(4))) unsigned uintx4;

constexpr int NAc = 4096;     // atoms
constexpr int NEc = 65536;    // edges
constexpr int NTc = 262144;   // triplets
constexpr float PI_F = 3.14159265358979323846f;
constexpr float SQ25 = 0.63245553203367587f;   // sqrt(2/5)

__device__ __forceinline__ float bf2f(unsigned short h){ return __uint_as_float(((unsigned)h)<<16); }
__device__ __forceinline__ unsigned short f2bf(float f){
  unsigned u = __float_as_uint(f);
  u += 0x7fffu + ((u>>16)&1u);
  return (unsigned short)(u>>16);
}
__device__ __forceinline__ float swishf(float x){ return x/(1.f+__expf(-x)); }

__device__ __forceinline__ floatx4 mfma16x16x32bf(shortx8 a, shortx8 b, floatx4 c){
  floatx4 d;
  asm("v_mfma_f32_16x16x32_bf16 %0, %1, %2, %3" : "=v"(d) : "v"(a), "v"(b), "v"(c));
  return d;
}

// ---------------- geometry ----------------
__global__ __launch_bounds__(256)
void egeom_k(const float* __restrict__ R, const int* __restrict__ ei,
             const int* __restrict__ ej, float* __restrict__ Dij, float* __restrict__ rbf){
  int e = blockIdx.x*256 + threadIdx.x;
  int i = ei[e], j = ej[e];
  float dx = R[i*3+0]-R[j*3+0];
  float dy = R[i*3+1]-R[j*3+1];
  float dz = R[i*3+2]-R[j*3+2];
  float d2 = dx*dx+dy*dy+dz*dz;
  float D = sqrtf(fmaxf(d2, 0.f));
  Dij[e] = D;
  float d = fmaxf(D, 1e-6f);
  float s = PI_F*d*0.2f;
  float sn, cs; sincosf(s, &sn, &cs);
  float invd = SQ25/d;
  float sprev = 0.f, scur = sn;
  #pragma unroll
  for (int q=0;q<6;q++){
    rbf[e*6+q] = scur*invd;
    float nx = 2.f*cs*scur - sprev; sprev = scur; scur = nx;
  }
}

// sorted-order triplet geometry: thread p handles w = tperm[p].
// Writes angp[p][16] AoS (coalesced) + tmeta[p] = texp[w].
__global__ __launch_bounds__(256)
void tgeom_k(const float* __restrict__ R, const int* __restrict__ t3i,
             const int* __restrict__ t3j, const int* __restrict__ t3k,
             const int* __restrict__ texp, const int* __restrict__ tperm,
             const float* __restrict__ Dij, float* __restrict__ angp,
             int* __restrict__ tmeta){
  int p = blockIdx.x*256 + threadIdx.x;
  int w = tperm[p];
  int ia = t3i[w], ja = t3j[w], ka = t3k[w];
  int e  = texp[w];
  tmeta[p] = e;
  float xi = R[ia*3+0], yi = R[ia*3+1], zi = R[ia*3+2];
  float r1x = R[ja*3+0]-xi, r1y = R[ja*3+1]-yi, r1z = R[ja*3+2]-zi;
  float r2x = R[ka*3+0]-xi, r2y = R[ka*3+1]-yi, r2z = R[ka*3+2]-zi;
  float dt = r1x*r2x + r1y*r2y + r1z*r2z;
  float cx = r1y*r2z - r1z*r2y;
  float cy = r1z*r2x - r1x*r2z;
  float cz = r1x*r2y - r1y*r2x;
  float yv = sqrtf(cx*cx + cy*cy + cz*cz);
  float h = sqrtf(dt*dt + yv*yv);
  float c1 = (h > 0.f) ? dt/h : 1.f;   // cos(atan2(y,x))
  float f[16];
  f[0] = 1.f; f[1] = c1;
  float cprev = 1.f, ccur = c1;
  #pragma unroll
  for (int l=2;l<7;l++){
    float nx = 2.f*c1*ccur - cprev; cprev = ccur; ccur = nx;
    f[l] = nx;
  }
  float d = fmaxf(Dij[e], 1e-6f);
  float s = PI_F*d*0.2f;
  float sn, cs; sincosf(s, &sn, &cs);
  float invd = 1.f/d;
  float sprev = 0.f, scur = sn;
  #pragma unroll
  for (int q=0;q<7;q++){
    f[7+q] = scur*invd;
    float nx = 2.f*cs*scur - sprev; sprev = scur; scur = nx;
  }
  f[14] = 0.f; f[15] = 0.f;
  float4* op = (float4*)(angp + (size_t)p*16);
  op[0] = (float4){f[0],f[1],f[2],f[3]};
  op[1] = (float4){f[4],f[5],f[6],f[7]};
  op[2] = (float4){f[8],f[9],f[10],f[11]};
  op[3] = (float4){f[12],f[13],f[14],f[15]};
}

// ---------------- weight prep (fp32 -> bf16, transpose to [N,K]) ----------------
// Wjk: concat [ji rows 0..127 | kj rows 128..255] per layer
__global__ __launch_bounds__(256)
void prep_transpose(const float* __restrict__ Wemb, const float* __restrict__ Wji,
                    const float* __restrict__ Wkj, const float* __restrict__ Wfin,
                    unsigned short* __restrict__ dW12, unsigned short* __restrict__ dWjk,
                    unsigned short* __restrict__ dWfin){
  int y = blockIdx.y;
  int x = blockIdx.x*256 + threadIdx.x;
  if (y == 0){
    if (x < 32768){
      int n = x >> 8, k = x & 255;
      dW12[x] = f2bf(Wemb[k*128 + n]);
    }
  } else {
    if (x < 16384){
      int n = x >> 7, k = x & 127;
      const float* s; unsigned short* d;
      if (y <= 7)      { s = Wji  + (y-1)*16384;  d = dWjk  + (y-1)*32768; }
      else if (y <= 14){ s = Wkj  + (y-8)*16384;  d = dWjk  + (y-8)*32768 + 16384; }
      else             { s = Wfin + (y-15)*16384; d = dWfin + (y-15)*16384; }
      d[x] = f2bf(s[k*128 + n]);
    }
  }
}

// Wbil [j,l,i] -> Wbilt [i][k=(j*8+l)]  (plain [1024,128] transpose per layer)
__global__ __launch_bounds__(256)
void prep_wbil(const float* __restrict__ Wbil, unsigned short* __restrict__ dst){
  int x = blockIdx.x*256 + threadIdx.x;
  if (x < 7*131072){
    int i = x >> 17; int rem = x & 131071;
    int o = rem >> 10; int k = rem & 1023;
    dst[x] = f2bf(Wbil[(size_t)i*131072 + (size_t)k*128 + o]);
  }
}

__global__ __launch_bounds__(256)
void prep_emb(const float* __restrict__ emb, unsigned short* __restrict__ d){
  int x = blockIdx.x*256 + threadIdx.x;
  if (x < 95*128) d[x] = f2bf(emb[x]);
}

// ---------------- counting sort ----------------
__global__ __launch_bounds__(256)
void hist_k(const int* __restrict__ ids, int n, int* __restrict__ hist){
  int stride = gridDim.x*blockDim.x;
  for (int x = blockIdx.x*blockDim.x + threadIdx.x; x < n; x += stride)
    atomicAdd(&hist[ids[x]], 1);
}

// hierarchical scan: nbins <= 65536, nbins % 256 == 0, nbins/256 <= 256
__global__ __launch_bounds__(256)
void scan1_k(const int* __restrict__ hist, int* __restrict__ offs, int* __restrict__ bsum){
  __shared__ int buf[256];
  int t = threadIdx.x;
  int x = blockIdx.x*256 + t;
  int v = hist[x];
  buf[t] = v; __syncthreads();
  #pragma unroll
  for (int d=1; d<256; d<<=1){
    int u = (t>=d) ? buf[t-d] : 0;
    __syncthreads(); buf[t] += u; __syncthreads();
  }
  offs[x] = buf[t] - v;                 // exclusive within block
  if (t == 255) bsum[blockIdx.x] = buf[255];
}

__global__ __launch_bounds__(256)
void scan2_k(int* __restrict__ bsum, int nb){
  __shared__ int buf[256];
  int t = threadIdx.x;
  int v = (t < nb) ? bsum[t] : 0;
  buf[t] = v; __syncthreads();
  #pragma unroll
  for (int d=1; d<256; d<<=1){
    int u = (t>=d) ? buf[t-d] : 0;
    __syncthreads(); buf[t] += u; __syncthreads();
  }
  if (t < nb) bsum[t] = buf[t] - v;     // exclusive
}

__global__ __launch_bounds__(256)
void scan3_k(const int* __restrict__ hist, int* __restrict__ offs,
             const int* __restrict__ bsum, int nbins){
  int x = blockIdx.x*256 + threadIdx.x;
  int o = offs[x] + bsum[blockIdx.x];
  offs[x] = o;
  if (x == nbins-1) offs[nbins] = o + hist[x];
}

__global__ __launch_bounds__(256)
void scatter_k(const int* __restrict__ ids, int n, const int* __restrict__ offs,
               int* __restrict__ cursor, int* __restrict__ perm){
  int stride = gridDim.x*blockDim.x;
  for (int x = blockIdx.x*blockDim.x + threadIdx.x; x < n; x += stride){
    int b = ids[x];
    int pos = offs[b] + atomicAdd(&cursor[b], 1);
    perm[pos] = x;
  }
}

// ---------------- sb = sbf @ Wsbf[i]  [T,8] (sorted order, streaming) ----------------
__global__ __launch_bounds__(256)
void sb_k(const float* __restrict__ angp, const float* __restrict__ Wsbf,
          float* __restrict__ sb){
  __shared__ float Ws[392];
  for (int x = threadIdx.x; x < 392; x += 256) Ws[x] = Wsbf[x];
  __syncthreads();
  int p = blockIdx.x*256 + threadIdx.x;
  const float4* ap = (const float4*)(angp + (size_t)p*16);
  float4 a0 = ap[0], a1 = ap[1], a2 = ap[2], a3 = ap[3];
  float ca[7] = {a0.x,a0.y,a0.z,a0.w,a1.x,a1.y,a1.z};
  float rd[7] = {a1.w,a2.x,a2.y,a2.z,a2.w,a3.x,a3.y};
  float o[8] = {0,0,0,0,0,0,0,0};
  #pragma unroll
  for (int a=0;a<7;a++){
    #pragma unroll
    for (int r=0;r<7;r++){
      float pr = ca[a]*rd[r];
      const float* wp = &Ws[(a*7+r)*8];
      #pragma unroll
      for (int l=0;l<8;l++) o[l] += pr*wp[l];
    }
  }
  float4* op = (float4*)(sb + (size_t)p*8);
  op[0] = (float4){o[0],o[1],o[2],o[3]};
  op[1] = (float4){o[4],o[5],o[6],o[7]};
}

// ---------------- G[r, j*8+l] = sum_{w in r} sb[w,l]*xkj[exp[w],j]  (wave/edge, 4-deep MLP) ----------------
__global__ __launch_bounds__(256)
void gbuild_k(int c0, const int* __restrict__ toffs, const int* __restrict__ tmeta,
              const float* __restrict__ sb, const unsigned short* __restrict__ xkj,
              unsigned short* __restrict__ G){
  int lane = threadIdx.x & 63;
  int wv = __builtin_amdgcn_readfirstlane(threadIdx.x >> 6);
  int r = c0 + blockIdx.x*4 + wv;
  float acc0[8] = {}, acc1[8] = {};
  int s = toffs[r], e_ = toffs[r+1];
  for (int t = s; t < e_; t += 4){
    int tl = e_ - 1;
    int t1 = (t+1 < e_) ? t+1 : tl;
    int t2 = (t+2 < e_) ? t+2 : tl;
    int t3 = (t+3 < e_) ? t+3 : tl;
    float w1 = (t+1 < e_) ? 1.f : 0.f;
    float w2 = (t+2 < e_) ? 1.f : 0.f;
    float w3 = (t+3 < e_) ? 1.f : 0.f;
    int e0 = tmeta[t], e1 = tmeta[t1], e2 = tmeta[t2], e3 = tmeta[t3];
    unsigned xv0 = *(const unsigned*)&xkj[(size_t)e0*128 + lane*2];
    unsigned xv1 = *(const unsigned*)&xkj[(size_t)e1*128 + lane*2];
    unsigned xv2 = *(const unsigned*)&xkj[(size_t)e2*128 + lane*2];
    unsigned xv3 = *(const unsigned*)&xkj[(size_t)e3*128 + lane*2];
    float4 sa0 = *(const float4*)&sb[(size_t)t *8];
    float4 sc0 = *(const float4*)&sb[(size_t)t *8 + 4];
    float4 sa1 = *(const float4*)&sb[(size_t)t1*8];
    float4 sc1 = *(const float4*)&sb[(size_t)t1*8 + 4];
    float4 sa2 = *(const float4*)&sb[(size_t)t2*8];
    float4 sc2 = *(const float4*)&sb[(size_t)t2*8 + 4];
    float4 sa3 = *(const float4*)&sb[(size_t)t3*8];
    float4 sc3 = *(const float4*)&sb[(size_t)t3*8 + 4];
    float x00 = bf2f((unsigned short)(xv0 & 0xffffu));
    float x01 = bf2f((unsigned short)(xv0 >> 16));
    float x10 = bf2f((unsigned short)(xv1 & 0xffffu)) * w1;
    float x11 = bf2f((unsigned short)(xv1 >> 16)) * w1;
    float x20 = bf2f((unsigned short)(xv2 & 0xffffu)) * w2;
    float x21 = bf2f((unsigned short)(xv2 >> 16)) * w2;
    float x30 = bf2f((unsigned short)(xv3 & 0xffffu)) * w3;
    float x31 = bf2f((unsigned short)(xv3 >> 16)) * w3;
    acc0[0] += sa0.x*x00 + sa1.x*x10 + sa2.x*x20 + sa3.x*x30;
    acc1[0] += sa0.x*x01 + sa1.x*x11 + sa2.x*x21 + sa3.x*x31;
    acc0[1] += sa0.y*x00 + sa1.y*x10 + sa2.y*x20 + sa3.y*x30;
    acc1[1] += sa0.y*x01 + sa1.y*x11 + sa2.y*x21 + sa3.y*x31;
    acc0[2] += sa0.z*x00 + sa1.z*x10 + sa2.z*x20 + sa3.z*x30;
    acc1[2] += sa0.z*x01 + sa1.z*x11 + sa2.z*x21 + sa3.z*x31;
    acc0[3] += sa0.w*x00 + sa1.w*x10 + sa2.w*x20 + sa3.w*x30;
    acc1[3] += sa0.w*x01 + sa1.w*x11 + sa2.w*x21 + sa3.w*x31;
    acc0[4] += sc0.x*x00 + sc1.x*x10 + sc2.x*x20 + sc3.x*x30;
    acc1[4] += sc0.x*x01 + sc1.x*x11 + sc2.x*x21 + sc3.x*x31;
    acc0[5] += sc0.y*x00 + sc1.y*x10 + sc2.y*x20 + sc3.y*x30;
    acc1[5] += sc0.y*x01 + sc1.y*x11 + sc2.y*x21 + sc3.y*x31;
    acc0[6] += sc0.z*x00 + sc1.z*x10 + sc2.z*x20 + sc3.z*x30;
    acc1[6] += sc0.z*x01 + sc1.z*x11 + sc2.z*x21 + sc3.z*x31;
    acc0[7] += sc0.w*x00 + sc1.w*x10 + sc2.w*x20 + sc3.w*x30;
    acc1[7] += sc0.w*x01 + sc1.w*x11 + sc2.w*x21 + sc3.w*x31;
  }
  size_t base = (size_t)(r - c0)*1024 + (size_t)lane*16;
  uintx4 v0, v1;
  #pragma unroll
  for (int d=0; d<4; d++){
    v0[d] = (unsigned)f2bf(acc0[2*d]) | ((unsigned)f2bf(acc0[2*d+1]) << 16);
    v1[d] = (unsigned)f2bf(acc1[2*d]) | ((unsigned)f2bf(acc1[2*d+1]) << 16);
  }
  *(uintx4*)&G[base]     = v0;
  *(uintx4*)&G[base + 8] = v1;
}

// ---------------- generic MFMA GEMM (M=64 tile): C[M,128] = A[M,K] @ Bt[128,K]^T ----------------
// R11 post-mortem: 128-row tiles -> 512 blocks -> 2 waves/SIMD, latency-bound (48.7us,
// MfmaUtil 3%, 1.07 TB/s). M=64 -> 1024+ blocks -> 4 waves/SIMD, LDS 27.6KB.
// Wave grid 2x2: each wave 32 rows x 64 cols, acc[2][4].
// MODE 0: A direct bf16 [rows, K]. MODE 1: embedding gather.
// EPI 0: m0 = swish(acc + b + rbf@Wemb_tail) -> outF(m f32) + outB(m bf16)
// EPI 3: acc + xji -> outB (afin)
// EPI 4: m += swish(acc + bias) -> outF(m) + outB(m bf16)
// EPI 5: dual (grid.y): y0 -> swish(acc+bias) -> outB (xji); y1 -> swish(acc+bias2)*(rbf@W6) -> outB2 (xkj)
template<int MODE, int EPI>
__global__ __launch_bounds__(256)
void gemm_k(const unsigned short* __restrict__ A, const unsigned short* __restrict__ Bt,
            int K, int rowoff, int arow0,
            const int* __restrict__ gi, const int* __restrict__ gj, const int* __restrict__ Zr,
            const float* __restrict__ rbfp, const float* __restrict__ W6,
            const float* __restrict__ bias, const float* __restrict__ bias2,
            const float* minp, const unsigned short* __restrict__ xjip,
            float* outF, unsigned short* outB, unsigned short* outB2){
  __shared__ __align__(16) unsigned short As[64*72];
  __shared__ __align__(16) unsigned short Bs[128*72];
  const int tid = threadIdx.x;
  const int lane = tid & 63;
  const int wid = tid >> 6;
  const int wr = wid >> 1, wc = wid & 1;
  const int rowbase = rowoff + blockIdx.x*64;
  const int brow0 = (EPI==5) ? (int)blockIdx.y*128 : 0;
  floatx4 acc[2][4];
  #pragma unroll
  for (int i=0;i<2;i++)
    #pragma unroll
    for (int j=0;j<4;j++) acc[i][j] = (floatx4){0.f,0.f,0.f,0.f};

  for (int k0 = 0; k0 < K; k0 += 64){
    shortx8 ra[2], rb[4];
    #pragma unroll
    for (int q=0;q<2;q++){                 // A: 64 rows x 64 k = 512 shortx8
      int c = q*256 + tid;
      int row = c >> 3;
      int ko = (c & 7) << 3;
      const unsigned short* asrc;
      if (MODE == 0){
        asrc = A + (size_t)(rowbase - arow0 + row)*K + k0 + ko;
      } else {
        int grow = rowbase + row;
        int kg = k0 + ko;
        int atom = (kg < 128) ? gi[grow] : gj[grow];
        asrc = A + (size_t)Zr[atom]*128 + (kg & 127);
      }
      ra[q] = *(const shortx8*)asrc;
    }
    #pragma unroll
    for (int q=0;q<4;q++){                 // B: 128 rows x 64 k = 1024 shortx8
      int c = q*256 + tid;
      int row = c >> 3;
      int ko = (c & 7) << 3;
      rb[q] = *(const shortx8*)(Bt + (size_t)(brow0 + row)*K + k0 + ko);
    }
    __syncthreads();
    #pragma unroll
    for (int q=0;q<2;q++){
      int c = q*256 + tid;
      *(shortx8*)&As[(c>>3)*72 + ((c&7)<<3)] = ra[q];
    }
    #pragma unroll
    for (int q=0;q<4;q++){
      int c = q*256 + tid;
      *(shortx8*)&Bs[(c>>3)*72 + ((c&7)<<3)] = rb[q];
    }
    __syncthreads();
    #pragma unroll
    for (int kk=0; kk<2; kk++){
      shortx8 af[2], bfr[4];
      #pragma unroll
      for (int mi=0;mi<2;mi++)
        af[mi] = *(const shortx8*)&As[(wr*32 + mi*16 + (lane&15))*72 + kk*32 + ((lane>>4)<<3)];
      #pragma unroll
      for (int ni=0;ni<4;ni++)
        bfr[ni] = *(const shortx8*)&Bs[(wc*64 + ni*16 + (lane&15))*72 + kk*32 + ((lane>>4)<<3)];
      #pragma unroll
      for (int mi=0;mi<2;mi++)
        #pragma unroll
        for (int ni=0;ni<4;ni++)
          acc[mi][ni] = mfma16x16x32bf(af[mi], bfr[ni], acc[mi][ni]);
    }
  }
  asm volatile("s_nop 7\ns_nop 7\ns_nop 7");   // MFMA->VALU hazard guard

  #pragma unroll
  for (int mi=0;mi<2;mi++){
    #pragma unroll
    for (int j=0;j<4;j++){
      int row = wr*32 + mi*16 + ((lane>>4)<<2) + j;   // C/D: row=(lane>>4)*4+reg  [m89]
      int grow = rowbase + row;
      float rb6[6];
      bool needr = (EPI==0) || ((EPI==5) && blockIdx.y==1);
      if (needr){
        #pragma unroll
        for (int q=0;q<6;q++) rb6[q] = rbfp[grow*6+q];
      }
      #pragma unroll
      for (int ni=0;ni<4;ni++){
        int col = wc*64 + ni*16 + (lane&15);           // C/D: col=lane&15
        float v = acc[mi][ni][j];
        size_t oidx = (size_t)grow*128 + col;
        if (EPI==0){
          float e = bias[col];
          #pragma unroll
          for (int q=0;q<6;q++) e += rb6[q]*W6[q*128+col];
          v = swishf(v + e);
          outF[oidx] = v;
          outB[oidx] = f2bf(v);
        } else if (EPI==3){
          v += bf2f(xjip[oidx]);
          outB[oidx] = f2bf(v);
        } else if (EPI==4){
          float nm = minp[oidx] + swishf(v + bias[col]);
          outF[oidx] = nm;
          outB[oidx] = f2bf(nm);
        } else { // EPI==5
          if (blockIdx.y == 0){
            v = swishf(v + bias[col]);
            outB[oidx] = f2bf(v);
          } else {
            float rp = 0.f;
            #pragma unroll
            for (int q=0;q<6;q++) rp += rb6[q]*W6[q*128+col];
            v = swishf(v + bias2[col]) * rp;
            outB2[oidx] = f2bf(v);
          }
        }
      }
    }
  }
}

// ---------------- out_layer: wave per atom ----------------
__global__ __launch_bounds__(256)
void out_layer_k(const int* __restrict__ eperm, const int* __restrict__ eoffs,
                 const unsigned short* __restrict__ mbf, const float* __restrict__ rbf,
                 const float* __restrict__ Wrbf, const float* __restrict__ W1,
                 const float* __restrict__ b1, const float* __restrict__ W2,
                 const int* __restrict__ bseg, float* __restrict__ out){
  __shared__ float ta_lds[4][128];
  int lane = threadIdx.x & 63;
  int wv = __builtin_amdgcn_readfirstlane(threadIdx.x >> 6);
  int a = blockIdx.x*4 + wv;
  int f0 = lane*2;
  float wr0[6], wr1[6];
  #pragma unroll
  for (int q=0;q<6;q++){ wr0[q] = Wrbf[q*128+f0]; wr1[q] = Wrbf[q*128+f0+1]; }
  float ta0 = 0.f, ta1 = 0.f;
  int s = eoffs[a], e_ = eoffs[a+1];
  for (int t = s; t < e_; t++){
    int e = eperm[t];
    unsigned mv = *(const unsigned*)&mbf[(size_t)e*128 + f0];
    float r0 = rbf[e*6+0], r1 = rbf[e*6+1], r2 = rbf[e*6+2];
    float r3 = rbf[e*6+3], r4 = rbf[e*6+4], r5 = rbf[e*6+5];
    float rp0 = r0*wr0[0]+r1*wr0[1]+r2*wr0[2]+r3*wr0[3]+r4*wr0[4]+r5*wr0[5];
    float rp1 = r0*wr1[0]+r1*wr1[1]+r2*wr1[2]+r3*wr1[3]+r4*wr1[4]+r5*wr1[5];
    ta0 += bf2f((unsigned short)(mv & 0xffffu))*rp0;
    ta1 += bf2f((unsigned short)(mv >> 16))*rp1;
  }
  ta_lds[wv][f0]   = ta0;
  ta_lds[wv][f0+1] = ta1;
  float p = 0.f;
  #pragma unroll
  for (int h=0; h<2; h++){
    int n = lane + h*64;
    float o = b1[n];
    for (int f=0; f<128; f++) o += ta_lds[wv][f]*W1[f*128+n];
    p += swishf(o)*W2[n];
  }
  #pragma unroll
  for (int off=32; off; off>>=1) p += __shfl_down(p, off);
  if (lane == 0) atomicAdd(&out[bseg[a]], p);
}

// ---------------- launch ----------------
extern "C" void kernel_launch(void* const* d_in, const int* in_sizes, int n_in,
                              void* d_out, int out_size, void* d_ws, size_t ws_size,
                              hipStream_t stream){
  const int*   Z    = (const int*)d_in[0];
  const float* R    = (const float*)d_in[1];
  const int*   bseg = (const int*)d_in[2];
  const int*   ei   = (const int*)d_in[3];
  const int*   ej   = (const int*)d_in[4];
  const int*   texp = (const int*)d_in[5];
  const int*   tred = (const int*)d_in[6];
  const int*   t3i  = (const int*)d_in[7];
  const int*   t3j  = (const int*)d_in[8];
  const int*   t3k  = (const int*)d_in[9];
  const float* emb  = (const float*)d_in[10];
  const float* Wemb = (const float*)d_in[11];
  const float* bemb = (const float*)d_in[12];
  const float* oWr  = (const float*)d_in[13];
  const float* oW1  = (const float*)d_in[14];
  const float* ob1  = (const float*)d_in[15];
  const float* oW2  = (const float*)d_in[16];
  const float* iWr  = (const float*)d_in[17];
  const float* iWs  = (const float*)d_in[18];
  const float* iWkj = (const float*)d_in[19];
  const float* ibkj = (const float*)d_in[20];
  const float* iWji = (const float*)d_in[21];
  const float* ibji = (const float*)d_in[22];
  const float* iWb  = (const float*)d_in[23];
  const float* iWf  = (const float*)d_in[24];
  const float* ibf  = (const float*)d_in[25];
  float* out = (float*)d_out;

  char* p = (char*)d_ws;
  auto alloc = [&](size_t bytes)->char*{ char* r = p; p += (bytes + 255) & ~(size_t)255; return r; };
  float* Dij    = (float*)alloc((size_t)NEc*4);
  float* rbf    = (float*)alloc((size_t)NEc*6*4);
  float* angp   = (float*)alloc((size_t)NTc*16*4);
  float* sball  = (float*)alloc((size_t)NTc*8*4);
  float* m      = (float*)alloc((size_t)NEc*128*4);
  unsigned short* mbf  = (unsigned short*)alloc((size_t)NEc*128*2);
  unsigned short* xji  = (unsigned short*)alloc((size_t)NEc*128*2);
  unsigned short* xkj  = (unsigned short*)alloc((size_t)NEc*128*2);
  unsigned short* afin = (unsigned short*)alloc((size_t)NEc*128*2);
  int* thist = (int*)alloc((size_t)NEc*4);
  int* toffs = (int*)alloc((size_t)(NEc+1)*4);
  int* tperm = (int*)alloc((size_t)NTc*4);
  int* tmeta = (int*)alloc((size_t)NTc*4);
  int* ehist = (int*)alloc((size_t)NAc*4);
  int* eoffs = (int*)alloc((size_t)(NAc+1)*4);
  int* eperm = (int*)alloc((size_t)NEc*4);
  int* bsum  = (int*)alloc((size_t)257*4);
  unsigned short* embbf = (unsigned short*)alloc((size_t)95*128*2);
  unsigned short* W12et = (unsigned short*)alloc((size_t)128*256*2);
  unsigned short* Wjkt  = (unsigned short*)alloc((size_t)7*32768*2);
  unsigned short* Wfint = (unsigned short*)alloc((size_t)7*16384*2);
  unsigned short* Wbilt = (unsigned short*)alloc((size_t)7*131072*2);
  size_t fixed = (size_t)(p - (char*)d_ws);

  // choose G chunking to fit workspace
  int nch = 1;
  while (nch < 8 && fixed + ((size_t)NEc/nch)*1024*2 > ws_size) nch <<= 1;
  int ECH = NEc / nch;
  unsigned short* Gbuf = (unsigned short*)alloc((size_t)ECH*1024*2);

  hipMemsetAsync(d_out, 0, 64*sizeof(float), stream);
  hipMemsetAsync(thist, 0, (size_t)NEc*4, stream);
  hipMemsetAsync(ehist, 0, (size_t)NAc*4, stream);

  prep_transpose<<<dim3(128,22),256,0,stream>>>(Wemb, iWji, iWkj, iWf, W12et, Wjkt, Wfint);
  prep_wbil<<<3584,256,0,stream>>>(iWb, Wbilt);
  prep_emb<<<48,256,0,stream>>>(emb, embbf);
  egeom_k<<<NEc/256,256,0,stream>>>(R, ei, ej, Dij, rbf);

  // triplet sort by id_reduce_ji
  hist_k<<<512,256,0,stream>>>(tred, NTc, thist);
  scan1_k<<<NEc/256,256,0,stream>>>(thist, toffs, bsum);
  scan2_k<<<1,256,0,stream>>>(bsum, NEc/256);
  scan3_k<<<NEc/256,256,0,stream>>>(thist, toffs, bsum, NEc);
  hipMemsetAsync(thist, 0, (size_t)NEc*4, stream);
  scatter_k<<<512,256,0,stream>>>(tred, NTc, toffs, thist, tperm);
  // edge sort by idnb_i
  hist_k<<<256,256,0,stream>>>(ei, NEc, ehist);
  scan1_k<<<NAc/256,256,0,stream>>>(ehist, eoffs, bsum);
  scan2_k<<<1,256,0,stream>>>(bsum, NAc/256);
  scan3_k<<<NAc/256,256,0,stream>>>(ehist, eoffs, bsum, NAc);
  hipMemsetAsync(ehist, 0, (size_t)NAc*4, stream);
  scatter_k<<<256,256,0,stream>>>(ei, NEc, eoffs, ehist, eperm);

  // sorted-order triplet geometry
  tgeom_k<<<NTc/256,256,0,stream>>>(R, t3i, t3j, t3k, texp, tperm, Dij, angp, tmeta);

  // m0 = swish([h_i,h_j,rbf] @ W_emb + b)
  gemm_k<1,0><<<NEc/64,256,0,stream>>>(embbf, W12et, 256, 0, 0, ei, ej, Z,
      rbf, Wemb + 256*128, bemb, nullptr, nullptr, nullptr, m, mbf, nullptr);
  out_layer_k<<<NAc/4,256,0,stream>>>(eperm, eoffs, mbf, rbf,
                                      oWr, oW1, ob1, oW2, bseg, out);

  for (int i=0;i<7;i++){
    sb_k<<<NTc/256,256,0,stream>>>(angp, iWs + i*392, sball);
    // dual GEMM: y=0 -> xji, y=1 -> xkj
    gemm_k<0,5><<<dim3(NEc/64,2),256,0,stream>>>(mbf, Wjkt + i*32768, 128, 0, 0,
        nullptr, nullptr, nullptr, rbf, iWr + i*768, ibji + i*128, ibkj + i*128,
        nullptr, nullptr, nullptr, xji, xkj);
    for (int c=0;c<nch;c++){
      int c0 = c*ECH;
      gbuild_k<<<ECH/4,256,0,stream>>>(c0, toffs, tmeta, sball, xkj, Gbuf);
      gemm_k<0,3><<<ECH/64,256,0,stream>>>(Gbuf, Wbilt + (size_t)i*131072, 1024, c0, c0,
          nullptr, nullptr, nullptr, nullptr, nullptr, nullptr, nullptr, nullptr,
          xji, nullptr, afin, nullptr);
    }
    gemm_k<0,4><<<NEc/64,256,0,stream>>>(afin, Wfint + i*16384, 128, 0, 0,
        nullptr, nullptr, nullptr, nullptr, nullptr, ibf + i*128, nullptr,
        m, nullptr, m, mbf, nullptr);
    out_layer_k<<<NAc/4,256,0,stream>>>(eperm, eoffs, mbf, rbf,
        oWr + (i+1)*768, oW1 + (i+1)*16384, ob1 + (i+1)*128, oW2 + (i+1)*128, bseg, out);
  }
  (void)in_sizes; (void)n_in; (void)out_size;
}